// Round 2
// baseline (347.518 us; speedup 1.0000x reference)
//
#include <hip/hip_runtime.h>
#include <hip/hip_bf16.h>

#define N_NODES 100000
#define N_EDGES 1600000
#define IN_F 128
#define OUT_F 32

typedef float vfloat2 __attribute__((ext_vector_type(2)));

// Packed 2xf32 atomic add (global_atomic_pk_add_f32), one op per 8 bytes.
__device__ inline void pk_atomic_add(float* addr, float a, float b) {
#if __has_builtin(__builtin_amdgcn_global_atomic_fadd_v2f32)
  vfloat2 v; v.x = a; v.y = b;
  __builtin_amdgcn_global_atomic_fadd_v2f32(
      (__attribute__((address_space(1))) vfloat2*)addr, v);
#else
  atomicAdd(addr, a);
  atomicAdd(addr + 1, b);
#endif
}

// ---------------- GEMM: support[N,32] = x[N,128] @ W[128,32] ----------------
// 256 threads = 32 rows x 8 feature-quads. Each thread computes 4 outputs:
// per k-iter, 1 LDS b32 (x, 8-way broadcast) + 1 LDS b128 (W) feeds 4 FMAs.
// x tile padded to 132 floats/row: 16B-aligned rows, banks (4r+k)%32 distinct
// across the 8 r-values in a wave -> conflict-free.
__global__ __launch_bounds__(256) void gcn_gemm_kernel(
    const float* __restrict__ x, const float* __restrict__ w,
    float* __restrict__ support) {
  __shared__ float wlds[IN_F][OUT_F];     // 16 KB
  __shared__ float xlds[32][IN_F + 4];    // 16.5 KB, padded
  const int tid = threadIdx.x;
  const int row0 = blockIdx.x * 32;       // 3125 * 32 = 100000 exactly

  // Stage W: 4096 floats = 1024 float4, 4 per thread.
  {
    const float4* wsrc = (const float4*)w;
    float4* wdst = (float4*)&wlds[0][0];
    #pragma unroll
    for (int i = 0; i < 4; ++i) wdst[tid + i * 256] = wsrc[tid + i * 256];
  }
  // Stage 32 x-rows: 1024 float4, 4 per thread, coalesced.
  {
    #pragma unroll
    for (int i = 0; i < 4; ++i) {
      const int idx = tid + i * 256;
      const int r = idx >> 5;        // 0..31
      const int c4 = idx & 31;       // float4 within row
      float4 v = ((const float4*)(x + (size_t)(row0 + r) * IN_F))[c4];
      *(float4*)&xlds[r][c4 * 4] = v;
    }
  }
  __syncthreads();

  const int fq = tid & 7;    // feature quad 0..7
  const int r = tid >> 3;    // row within tile 0..31
  float4 acc = make_float4(0.f, 0.f, 0.f, 0.f);
  #pragma unroll
  for (int k = 0; k < IN_F; ++k) {
    const float xv = xlds[r][k];
    const float4 wv = ((const float4*)&wlds[k][0])[fq];
    acc.x += xv * wv.x;
    acc.y += xv * wv.y;
    acc.z += xv * wv.z;
    acc.w += xv * wv.w;
  }
  ((float4*)(support + (size_t)(row0 + r) * OUT_F))[fq] = acc;
}

// ---------------- out init: out[n,f] = bias[f] (float4) ----------------
__global__ __launch_bounds__(256) void gcn_init_out_kernel(
    float* __restrict__ out, const float* __restrict__ bias) {
  const int i = blockIdx.x * 256 + threadIdx.x;  // float4 index
  if (i < N_NODES * OUT_F / 4)
    ((float4*)out)[i] = ((const float4*)bias)[i & 7];
}

// ---------------- scatter: out[row[e],:] += val[e] * support[col[e],:] ------
// 16 lanes per edge, one float2 + one packed atomic each. Gather and atomic
// destinations are 128B-contiguous per edge.
__global__ __launch_bounds__(256) void gcn_scatter_kernel(
    const float* __restrict__ support, const int* __restrict__ erow,
    const int* __restrict__ ecol, const float* __restrict__ eval,
    float* __restrict__ out) {
  const long long idx = (long long)blockIdx.x * 256 + threadIdx.x;
  if (idx >= (long long)N_EDGES * 16) return;
  const int e = (int)(idx >> 4);
  const int h = (int)(idx & 15);       // float2 slot 0..15
  const float v = eval[e];
  const int c = ecol[e];
  const int r = erow[e];
  const float2 s = ((const float2*)(support + (size_t)c * OUT_F))[h];
  pk_atomic_add(out + (size_t)r * OUT_F + h * 2, v * s.x, v * s.y);
}

extern "C" void kernel_launch(void* const* d_in, const int* in_sizes, int n_in,
                              void* d_out, int out_size, void* d_ws, size_t ws_size,
                              hipStream_t stream) {
  const float* x = (const float*)d_in[0];
  const int* erow = (const int*)d_in[1];
  const int* ecol = (const int*)d_in[2];
  const float* eval = (const float*)d_in[3];
  const float* w = (const float*)d_in[4];
  const float* bias = (const float*)d_in[5];
  float* out = (float*)d_out;
  float* support = (float*)d_ws;  // N_NODES * OUT_F floats = 12.8 MB

  // 1) support = x @ W
  gcn_gemm_kernel<<<N_NODES / 32, 256, 0, stream>>>(x, w, support);
  // 2) out = bias
  gcn_init_out_kernel<<<(N_NODES * OUT_F / 4 + 255) / 256, 256, 0, stream>>>(out, bias);
  // 3) scatter-add edges (packed f32x2 atomics)
  const long long total = (long long)N_EDGES * 16;
  gcn_scatter_kernel<<<(int)((total + 255) / 256), 256, 0, stream>>>(
      support, erow, ecol, eval, out);
}

// Round 3
// 275.738 us; speedup vs baseline: 1.2603x; 1.2603x over previous
//
#include <hip/hip_runtime.h>
#include <hip/hip_bf16.h>

#define N_NODES 100000
#define N_EDGES 1600000
#define IN_F 128
#define OUT_F 32

// ---------------- GEMM: support[N,32] = x[N,128] @ W[128,32] ----------------
__global__ __launch_bounds__(256) void gcn_gemm_kernel(
    const float* __restrict__ x, const float* __restrict__ w,
    float* __restrict__ support) {
  __shared__ float wlds[IN_F][OUT_F];     // 16 KB
  __shared__ float xlds[32][IN_F + 4];    // padded
  const int tid = threadIdx.x;
  const int row0 = blockIdx.x * 32;

  {
    const float4* wsrc = (const float4*)w;
    float4* wdst = (float4*)&wlds[0][0];
    #pragma unroll
    for (int i = 0; i < 4; ++i) wdst[tid + i * 256] = wsrc[tid + i * 256];
  }
  {
    #pragma unroll
    for (int i = 0; i < 4; ++i) {
      const int idx = tid + i * 256;
      const int r = idx >> 5;
      const int c4 = idx & 31;
      float4 v = ((const float4*)(x + (size_t)(row0 + r) * IN_F))[c4];
      *(float4*)&xlds[r][c4 * 4] = v;
    }
  }
  __syncthreads();

  const int fq = tid & 7;
  const int r = tid >> 3;
  float4 acc = make_float4(0.f, 0.f, 0.f, 0.f);
  #pragma unroll
  for (int k = 0; k < IN_F; ++k) {
    const float xv = xlds[r][k];
    const float4 wv = ((const float4*)&wlds[k][0])[fq];
    acc.x += xv * wv.x; acc.y += xv * wv.y;
    acc.z += xv * wv.z; acc.w += xv * wv.w;
  }
  ((float4*)(support + (size_t)(row0 + r) * OUT_F))[fq] = acc;
}

// ---------------- CSR build ----------------
__global__ __launch_bounds__(256) void gcn_zero_kernel(int* __restrict__ p, int n) {
  const int i = blockIdx.x * 256 + threadIdx.x;
  if (i < n) p[i] = 0;
}

__global__ __launch_bounds__(256) void gcn_hist_kernel(
    const int* __restrict__ erow, int* __restrict__ counts) {
  const int e = blockIdx.x * 256 + threadIdx.x;
  if (e < N_EDGES) atomicAdd(&counts[erow[e]], 1);
}

// Block-level exclusive scan over 1024 elements; writes partial into rowptr,
// block total into bsums.
__global__ __launch_bounds__(1024) void gcn_scan1_kernel(
    const int* __restrict__ counts, int* __restrict__ rowptr,
    int* __restrict__ bsums) {
  __shared__ int s[1024];
  const int t = threadIdx.x;
  const int i = blockIdx.x * 1024 + t;
  const int v = (i < N_NODES) ? counts[i] : 0;
  s[t] = v;
  __syncthreads();
  #pragma unroll
  for (int off = 1; off < 1024; off <<= 1) {
    int add = (t >= off) ? s[t - off] : 0;
    __syncthreads();
    s[t] += add;
    __syncthreads();
  }
  if (i < N_NODES) rowptr[i] = s[t] - v;  // exclusive, partial
  if (t == 1023) bsums[blockIdx.x] = s[1023];
}

// Single-block exclusive scan of up to 128 block sums (in place).
__global__ __launch_bounds__(128) void gcn_scan2_kernel(
    int* __restrict__ bsums, int nb) {
  __shared__ int s[128];
  const int t = threadIdx.x;
  const int v = (t < nb) ? bsums[t] : 0;
  s[t] = v;
  __syncthreads();
  #pragma unroll
  for (int off = 1; off < 128; off <<= 1) {
    int add = (t >= off) ? s[t - off] : 0;
    __syncthreads();
    s[t] += add;
    __syncthreads();
  }
  if (t < nb) bsums[t] = s[t] - v;  // exclusive
}

// Add block offsets; write final rowptr and the write-cursor copy wpos.
__global__ __launch_bounds__(1024) void gcn_scan3_kernel(
    int* __restrict__ rowptr, const int* __restrict__ bsums,
    int* __restrict__ wpos) {
  const int i = blockIdx.x * 1024 + threadIdx.x;
  if (i < N_NODES) {
    const int val = rowptr[i] + bsums[blockIdx.x];
    rowptr[i] = val;
    wpos[i] = val;
  }
  if (i == 0) rowptr[N_NODES] = N_EDGES;
}

// Scatter edges into CSR order as packed (col, val) pairs.
__global__ __launch_bounds__(256) void gcn_reorder_kernel(
    const int* __restrict__ erow, const int* __restrict__ ecol,
    const float* __restrict__ eval, int* __restrict__ wpos,
    int2* __restrict__ rcv) {
  const int e = blockIdx.x * 256 + threadIdx.x;
  if (e >= N_EDGES) return;
  const int r = erow[e];
  const int slot = atomicAdd(&wpos[r], 1);
  rcv[slot] = make_int2(ecol[e], __float_as_int(eval[e]));
}

// ---------------- gather: out[n,f] = bias[f] + sum_e val*support[col,f] -----
// 8 nodes per 256-thread block, 32 lanes per node (one per feature).
__global__ __launch_bounds__(256) void gcn_gather_kernel(
    const float* __restrict__ support, const int* __restrict__ rowptr,
    const int2* __restrict__ rcv, const float* __restrict__ bias,
    float* __restrict__ out) {
  const int n = blockIdx.x * 8 + (threadIdx.x >> 5);
  const int f = threadIdx.x & 31;
  if (n >= N_NODES) return;
  const int start = rowptr[n];
  const int end = rowptr[n + 1];
  float acc = 0.f;
  int e = start;
  for (; e + 1 < end; e += 2) {
    const int2 a = rcv[e];
    const int2 b = rcv[e + 1];
    const float sa = support[(size_t)a.x * OUT_F + f];
    const float sb = support[(size_t)b.x * OUT_F + f];
    acc += __int_as_float(a.y) * sa + __int_as_float(b.y) * sb;
  }
  if (e < end) {
    const int2 a = rcv[e];
    acc += __int_as_float(a.y) * support[(size_t)a.x * OUT_F + f];
  }
  out[(size_t)n * OUT_F + f] = acc + bias[f];
}

// ---------------- fallback (R1 proven path) ----------------
__global__ __launch_bounds__(256) void gcn_init_out_kernel(
    float* __restrict__ out, const float* __restrict__ bias) {
  const int i = blockIdx.x * 256 + threadIdx.x;
  if (i < N_NODES * OUT_F / 4)
    ((float4*)out)[i] = ((const float4*)bias)[i & 7];
}

__global__ __launch_bounds__(256) void gcn_scatter_kernel(
    const float* __restrict__ support, const int* __restrict__ erow,
    const int* __restrict__ ecol, const float* __restrict__ eval,
    float* __restrict__ out) {
  const long long idx = (long long)blockIdx.x * 256 + threadIdx.x;
  if (idx >= (long long)N_EDGES * OUT_F) return;
  const int e = (int)(idx >> 5);
  const int f = (int)(idx & 31);
  atomicAdd(&out[(size_t)erow[e] * OUT_F + f],
            eval[e] * support[(size_t)ecol[e] * OUT_F + f]);
}

extern "C" void kernel_launch(void* const* d_in, const int* in_sizes, int n_in,
                              void* d_out, int out_size, void* d_ws, size_t ws_size,
                              hipStream_t stream) {
  const float* x = (const float*)d_in[0];
  const int* erow = (const int*)d_in[1];
  const int* ecol = (const int*)d_in[2];
  const float* eval = (const float*)d_in[3];
  const float* w = (const float*)d_in[4];
  const float* bias = (const float*)d_in[5];
  float* out = (float*)d_out;
  char* ws = (char*)d_ws;

  // Workspace layout (1 KiB-aligned chunks)
  const size_t SUP_OFF = 0;                       // 12,800,000 B
  const size_t CNT_OFF = SUP_OFF + 12800000;      // 400,384 B (counts -> wpos)
  const size_t RP_OFF  = CNT_OFF + 400384;        // 400,384 B (rowptr, N+1)
  const size_t BS_OFF  = RP_OFF + 400384;         // 1,024 B (block sums)
  const size_t RCV_OFF = BS_OFF + 1024;           // 12,800,000 B (int2 pairs)
  const size_t NEEDED  = RCV_OFF + 12800000;

  float* support = (float*)(ws + SUP_OFF);

  // 1) support = x @ W
  gcn_gemm_kernel<<<N_NODES / 32, 256, 0, stream>>>(x, w, support);

  if (ws_size >= NEEDED) {
    int* counts = (int*)(ws + CNT_OFF);   // reused as wpos after scan
    int* rowptr = (int*)(ws + RP_OFF);
    int* bsums  = (int*)(ws + BS_OFF);
    int2* rcv   = (int2*)(ws + RCV_OFF);
    const int NB = (N_NODES + 1023) / 1024;  // 98 scan blocks

    gcn_zero_kernel<<<(N_NODES + 255) / 256, 256, 0, stream>>>(counts, N_NODES);
    gcn_hist_kernel<<<(N_EDGES + 255) / 256, 256, 0, stream>>>(erow, counts);
    gcn_scan1_kernel<<<NB, 1024, 0, stream>>>(counts, rowptr, bsums);
    gcn_scan2_kernel<<<1, 128, 0, stream>>>(bsums, NB);
    gcn_scan3_kernel<<<NB, 1024, 0, stream>>>(rowptr, bsums, counts);
    gcn_reorder_kernel<<<(N_EDGES + 255) / 256, 256, 0, stream>>>(
        erow, ecol, eval, counts, rcv);
    gcn_gather_kernel<<<(N_NODES + 7) / 8, 256, 0, stream>>>(
        support, rowptr, rcv, bias, out);
  } else {
    // Fallback: proven atomic scatter path
    gcn_init_out_kernel<<<(N_NODES * OUT_F / 4 + 255) / 256, 256, 0, stream>>>(out, bias);
    const long long total = (long long)N_EDGES * OUT_F;
    gcn_scatter_kernel<<<(int)((total + 255) / 256), 256, 0, stream>>>(
        support, erow, ecol, eval, out);
  }
}